// Round 7
// baseline (154.743 us; speedup 1.0000x reference)
//
#include <hip/hip_runtime.h>
#include <hip/hip_bf16.h>

// Fused 34->128->128->1 MLP, bf16 MFMA.
// R17 = R16 "wave-solo" with the grid sized to the RESOURCE limit.
// R16 post-mortem: structure clean (no spill at VGPR 244, conflicts -6.7x,
// absmax ok) but 79.5us: grid 1024 = 1 wave/SIMD = zero TLP; ~40% of
// cycles were naked stalls (MfmaUtil 26 + VALUBusy 36). Occupancy was
// GRID-limited: at 244 VGPRs the 2048-reg/SIMD pool fits 2 waves/SIMD.
// R17: grid 2048 (8 one-wave blocks/CU). No launch-bounds change -- the
// allocation stays 244 (R12/R13 taught: never force the allocator); the
// partner wave fills MFMA-latency + lgkmcnt gaps.
// Structure per wave (block = 64 thr, 1 wave):
//  - ALL weights resident: w0t[8][2], w1t[8][4], b0q/b1q, w2f[4] in the
//    unified VGPR/AGPR file; no H exchange, no barriers, no PART.
//  - R8a identity per-wave: phys h = (ob>>1)*32 + q*8 + (ob&1)*4 + r;
//    L0 C/D pairs pk2c-pack into L1 B-frags in registers; same packing
//    feeds L2 (W2 in A row 0, D[0][cl] = dot).
//  - LDS: wave-private A0 double-buffer (2x16x72 shorts = 4.6KB);
//    in-order per-wave DS queue + compiler lgkmcnt, zero barriers.
//  - 2-deep pipeline: stage c+S from regs, gathers for c+2S, scalars c+3S.
// Diet kept (verified R11-R16, absmax 0.00390625): pk2c clamp-fused cvt,
// L2-as-MFMA, biases ride first MFMA C operand.
// Spill tell: WRITE_SIZE == 3906KB <=> clean.

using bf16x8 = __attribute__((ext_vector_type(8))) short;   // 8 bf16 = 4 VGPRs
using f32x4  = __attribute__((ext_vector_type(4))) float;   // MFMA C/D

#define NPTS    1000000
#define NUMEMB  6572
#define HID     128
#define A0S     72          // A0 row stride in bf16 (144B, 16B-aligned rows)
#define CHUNKS  62500       // NPTS / 16 points-per-wave-tile
#define LASTC   (CHUNKS - 1)
#define NBLOCKS 2048        // 8 one-wave blocks/CU = 2 waves/SIMD at 244 VGPR
#define STRIDE  2048

__device__ __forceinline__ unsigned short bf16r(float f) {
    unsigned u;
    __builtin_memcpy(&u, &f, 4);
    u = (u + 0x7fffu + ((u >> 16) & 1u)) >> 16;
    return (unsigned short)u;
}
__device__ __forceinline__ unsigned pk2(float a, float b) {
    // packed RNE f32x2 -> bf16x2 (v_cvt_pk_bf16_f32 on gfx950)
    float2 f2; f2.x = a; f2.y = b;
    __hip_bfloat162 h = __float22bfloat162_rn(f2);
    unsigned u;
    __builtin_memcpy(&u, &h, 4);
    return u;
}
__device__ __forceinline__ unsigned pk2c(float a, float b) {
    // packed cvt with VOP3 clamp: result clamped to [0,1] — fuses clamp01
    unsigned r;
    asm("v_cvt_pk_bf16_f32 %0, %1, %2 clamp" : "=v"(r) : "v"(a), "v"(b));
    return r;
}

__global__ __launch_bounds__(64, 1)
void mlp_fused(const float* __restrict__ x,
               const float* __restrict__ emb,
               const float* __restrict__ em_table,
               const float* __restrict__ W0, const float* __restrict__ b0,
               const float* __restrict__ W1, const float* __restrict__ b1,
               const float* __restrict__ W2, const float* __restrict__ b2,
               float* __restrict__ out)
{
    __shared__ __align__(16) unsigned short A0[2 * 16 * A0S]; // double-buffer

    const int lane = threadIdx.x;
    const int q  = lane >> 4;    // MFMA quad
    const int cl = lane & 15;    // MFMA col/row-within-quad
    const int p  = lane >> 2;    // staging: point 0..15
    const int s  = lane & 3;     // staging: 8-dim segment

    // zero both buffers once (cols 34..63 must read 0; stage writes 0..33)
    for (int i = lane; i < 2 * 16 * A0S; i += 64) A0[i] = 0;

    // ---- one-time: ALL weights as A-fragments (permuted cols) ----
    // Output block ob in 0..7 -> phys h = (ob>>1)*32 + q*8 + (ob&1)*4 + r;
    // A-frag column for m=cl: col(ob) = (ob>>1)*32 + (cl>>2)*8 + (ob&1)*4 + (cl&3).
    bf16x8 w0t[8][2];   // [ob][kt]  W0 rows: k<32 em, k32/k33 = x0/x1
    #pragma unroll
    for (int ob = 0; ob < 8; ++ob) {
        const int col = (ob >> 1) * 32 + (cl >> 2) * 8 + (ob & 1) * 4 + (cl & 3);
        #pragma unroll
        for (int kt = 0; kt < 2; ++kt) {
            bf16x8 v;
            #pragma unroll
            for (int e = 0; e < 8; ++e) {
                const int k = kt * 32 + q * 8 + e;
                float val = 0.f;
                if (k < 32)       val = W0[(2 + k) * HID + col];
                else if (k == 32) val = W0[0 * HID + col];
                else if (k == 33) val = W0[1 * HID + col];
                v[e] = (short)bf16r(val);
            }
            w0t[ob][kt] = v;
        }
    }
    bf16x8 w1t[8][4];   // [ob][kt]  k rows indexed by PHYS h1 (phys==logical)
    #pragma unroll
    for (int ob = 0; ob < 8; ++ob) {
        const int col = (ob >> 1) * 32 + (cl >> 2) * 8 + (ob & 1) * 4 + (cl & 3);
        #pragma unroll
        for (int kt = 0; kt < 4; ++kt) {
            bf16x8 v;
            #pragma unroll
            for (int e = 0; e < 8; ++e)
                v[e] = (short)bf16r(W1[(kt * 32 + q * 8 + e) * HID + col]);
            w1t[ob][kt] = v;
        }
    }
    f32x4 b0q[8], b1q[8];
    #pragma unroll
    for (int ob = 0; ob < 8; ++ob) {
        #pragma unroll
        for (int r = 0; r < 4; ++r) {
            const int h = (ob >> 1) * 32 + q * 8 + (ob & 1) * 4 + r;
            b0q[ob][r] = b0[h];
            b1q[ob][r] = b1[h];
        }
    }
    bf16x8 w2f[4];      // L2 A-frag: row 0 = W2 (phys order), rows 1..15 = 0
    #pragma unroll
    for (int kt = 0; kt < 4; ++kt) {
        #pragma unroll
        for (int e = 0; e < 8; ++e)
            w2f[kt][e] = (cl == 0) ? (short)bf16r(W2[kt * 32 + q * 8 + e])
                                   : (short)0;
    }
    const float bias2 = b2[0];

    int c = blockIdx.x;

    // ---- prologue: stage chunk c into buf 0 (synchronous) ----
    {
        const int gp = c * 16 + p;
        const float fe0 = emb[gp];
        float2 xv0 = {0.f, 0.f};
        if (s == 0) xv0 = *(const float2*)(x + 2 * gp);
        const int e1 = (int)fe0;
        const int e2 = (e1 + 1 < NUMEMB) ? e1 + 1 : NUMEMB - 1;
        const float r = fe0 - (float)e1;
        const float4* p1 = (const float4*)(em_table + e1 * 32 + s * 8);
        const float4* p2 = (const float4*)(em_table + e2 * 32 + s * 8);
        const float4 a0v = p1[0], a1v = p1[1];
        const float4 c0v = p2[0], c1v = p2[1];
        uint4 d;
        d.x = pk2(a0v.x + (c0v.x - a0v.x) * r, a0v.y + (c0v.y - a0v.y) * r);
        d.y = pk2(a0v.z + (c0v.z - a0v.z) * r, a0v.w + (c0v.w - a0v.w) * r);
        d.z = pk2(a1v.x + (c1v.x - a1v.x) * r, a1v.y + (c1v.y - a1v.y) * r);
        d.w = pk2(a1v.z + (c1v.z - a1v.z) * r, a1v.w + (c1v.w - a1v.w) * r);
        *(uint4*)&A0[p * A0S + s * 8] = d;
        if (s == 0) *(unsigned*)&A0[p * A0S + 32] = pk2(xv0.x, xv0.y);
    }

    // ---- pipeline setup: state for chunks c+S (stage-next) and c+2S ----
    int cA = c + STRIDE;     if (cA > LASTC) cA = LASTC;
    int cB = c + 2 * STRIDE; if (cB > LASTC) cB = LASTC;
    const float feA = emb[cA * 16 + p];
    float feB = emb[cB * 16 + p];
    float2 xvA = {0.f, 0.f}, xvB = {0.f, 0.f};
    if (s == 0) {
        xvA = *(const float2*)(x + 2 * (cA * 16 + p));
        xvB = *(const float2*)(x + 2 * (cB * 16 + p));
    }
    float4 g1a, g1b, g2a, g2b;   // gathered em rows for chunk c+S
    float frA;
    {
        const int e1 = (int)feA;
        const int e2 = (e1 + 1 < NUMEMB) ? e1 + 1 : NUMEMB - 1;
        frA = feA - (float)e1;
        const float4* p1 = (const float4*)(em_table + e1 * 32 + s * 8);
        const float4* p2 = (const float4*)(em_table + e2 * 32 + s * 8);
        g1a = p1[0]; g1b = p1[1]; g2a = p2[0]; g2b = p2[1];
    }

    int buf = 0;
    for (; c < CHUNKS; c += STRIDE) {
        // 1. L0 B-frag reads for chunk c (written last iter; in-order DS)
        const int rowR = (buf * 16 + cl) * A0S;
        const bf16x8 bf0 = *(const bf16x8*)&A0[rowR + q * 8];
        const bf16x8 bf1 = *(const bf16x8*)&A0[rowR + 32 + q * 8];

        // 2. stage chunk c+S into buf^1 (fills the ds_read shadow)
        {
            const int rowW = ((buf ^ 1) * 16 + p) * A0S;
            uint4 d;
            d.x = pk2(g1a.x + (g2a.x - g1a.x) * frA, g1a.y + (g2a.y - g1a.y) * frA);
            d.y = pk2(g1a.z + (g2a.z - g1a.z) * frA, g1a.w + (g2a.w - g1a.w) * frA);
            d.z = pk2(g1b.x + (g2b.x - g1b.x) * frA, g1b.y + (g2b.y - g1b.y) * frA);
            d.w = pk2(g1b.z + (g2b.z - g1b.z) * frA, g1b.w + (g2b.w - g1b.w) * frA);
            *(uint4*)&A0[rowW + s * 8] = d;
            if (s == 0) *(unsigned*)&A0[rowW + 32] = pk2(xvA.x, xvA.y);
        }

        // 3. advance pipeline: gathers for c+2S (feB ready); scalars for c+3S
        {
            const int e1 = (int)feB;
            const int e2 = (e1 + 1 < NUMEMB) ? e1 + 1 : NUMEMB - 1;
            frA = feB - (float)e1;
            const float4* p1 = (const float4*)(em_table + e1 * 32 + s * 8);
            const float4* p2 = (const float4*)(em_table + e2 * 32 + s * 8);
            g1a = p1[0]; g1b = p1[1]; g2a = p2[0]; g2b = p2[1];
            xvA = xvB;
            int cC = c + 3 * STRIDE; if (cC > LASTC) cC = LASTC;
            feB = emb[cC * 16 + p];
            if (s == 0) xvB = *(const float2*)(x + 2 * (cC * 16 + p));
        }

        // 4. L0: all 128 h1 for this wave's 16 points, bias in C
        f32x4 acc[8];
        #pragma unroll
        for (int ob = 0; ob < 8; ++ob)
            acc[ob] = __builtin_amdgcn_mfma_f32_16x16x32_bf16(
                w0t[ob][0], bf0, b0q[ob], 0, 0, 0);
        #pragma unroll
        for (int ob = 0; ob < 8; ++ob)
            acc[ob] = __builtin_amdgcn_mfma_f32_16x16x32_bf16(
                w0t[ob][1], bf1, acc[ob], 0, 0, 0);

        // 5. pack h1: C/D frag pairs -> L1 B-frags, clamp fused (pk2c)
        bf16x8 h1f[4];
        #pragma unroll
        for (int kt = 0; kt < 4; ++kt) {
            const f32x4 v0 = acc[2 * kt], v1 = acc[2 * kt + 1];
            uint4 w;
            w.x = pk2c(v0[0], v0[1]);
            w.y = pk2c(v0[2], v0[3]);
            w.z = pk2c(v1[0], v1[1]);
            w.w = pk2c(v1[2], v1[3]);
            __builtin_memcpy(&h1f[kt], &w, 16);
        }

        // 6. L1: all register operands, bias in C at kt=0
        #pragma unroll
        for (int ob = 0; ob < 8; ++ob)
            acc[ob] = __builtin_amdgcn_mfma_f32_16x16x32_bf16(
                w1t[ob][0], h1f[0], b1q[ob], 0, 0, 0);
        #pragma unroll
        for (int kt = 1; kt < 4; ++kt)
            #pragma unroll
            for (int ob = 0; ob < 8; ++ob)
                acc[ob] = __builtin_amdgcn_mfma_f32_16x16x32_bf16(
                    w1t[ob][kt], h1f[kt], acc[ob], 0, 0, 0);

        // 7. pack h2 + L2 via MFMA (two parallel 2-chains), D[0][cl] = dot
        const f32x4 zero = {0.f, 0.f, 0.f, 0.f};
        f32x4 za = zero, zb = zero;
        #pragma unroll
        for (int kt = 0; kt < 4; ++kt) {
            const f32x4 v0 = acc[2 * kt], v1 = acc[2 * kt + 1];
            uint4 w;
            w.x = pk2c(v0[0], v0[1]);
            w.y = pk2c(v0[2], v0[3]);
            w.z = pk2c(v1[0], v1[1]);
            w.w = pk2c(v1[2], v1[3]);
            bf16x8 hf;
            __builtin_memcpy(&hf, &w, 16);
            if (kt < 2)
                za = __builtin_amdgcn_mfma_f32_16x16x32_bf16(w2f[kt], hf, za, 0, 0, 0);
            else
                zb = __builtin_amdgcn_mfma_f32_16x16x32_bf16(w2f[kt], hf, zb, 0, 0, 0);
        }
        const float z = za[0] + zb[0] + bias2;
        const float sig = __builtin_amdgcn_rcpf(1.f + __expf(-z));
        if (q == 0) out[c * 16 + cl] = sig;

        buf ^= 1;
    }
}

extern "C" void kernel_launch(void* const* d_in, const int* in_sizes, int n_in,
                              void* d_out, int out_size, void* d_ws, size_t ws_size,
                              hipStream_t stream) {
    const float* x   = (const float*)d_in[0];
    const float* emb = (const float*)d_in[1];
    const float* emt = (const float*)d_in[2];
    const float* W0  = (const float*)d_in[3];
    const float* b0  = (const float*)d_in[4];
    const float* W1  = (const float*)d_in[5];
    const float* b1  = (const float*)d_in[6];
    const float* W2  = (const float*)d_in[7];
    const float* b2  = (const float*)d_in[8];
    mlp_fused<<<NBLOCKS, 64, 0, stream>>>(x, emb, emt, W0, b0, W1, b1, W2, b2,
                                          (float*)d_out);
}

// Round 8
// 123.312 us; speedup vs baseline: 1.2549x; 1.2549x over previous
//
#include <hip/hip_runtime.h>
#include <hip/hip_bf16.h>

// Fused 34->128->128->1 MLP, bf16 MFMA, transposed GEMMs.
// R18 = R15 (best verified: 63.5us/dispatch) with the three in-loop
// __syncthreads() replaced by lgkmcnt-only barriers.
// Mechanism (guide §5, m97): __syncthreads compiles to
// s_waitcnt vmcnt(0) lgkmcnt(0) + s_barrier -- it drains ALL outstanding
// global loads at every barrier. R15's t+1 emb/x prefetch (issued between
// L0 and epi0) was force-drained at bar2 with ~100cyc cover => ~700-900cyc
// naked HBM latency per tile with every wave stalled. Dependency audit:
// bar1=A0 ds_writes, bar2=H0 ds_writes, bar3=PART ds_writes -- all LDS;
// NO barrier needs vmcnt. All global loads are consumed by the issuing
// wave (compiler inserts per-use vmcnt waits; use is a full tile later).
// Fix: asm("s_waitcnt lgkmcnt(0); s_barrier":::"memory") -- one asm block
// so no LDS op can be scheduled between wait and barrier (rule-#18 guard).
// R16/R17 post-mortem (wave-solo abandoned): full weight replication =
// ~370 unified regs/wave > 256 => hard 1 wave/SIMD, zero TLP, 79-88us.
// Diet (verified R11-R15, absmax 0.00390625): pk2c clamp-fused cvt,
// L2-as-MFMA (W2 in A row 0), biases ride first MFMA C, PART aliased in
// A0 cols 64..71 (LDS 26624B), no own[], w1r rotation (literal indices).
// R8a: phys h = nq*32 + q*8 + hb*4 + r; L0 C/D frag == L1 B frag layout.
// Spill tell: WRITE_SIZE == 3906.25KB <=> clean alloc at (256,3).

using bf16x8 = __attribute__((ext_vector_type(8))) short;   // 8 bf16 = 4 VGPRs
using f32x4  = __attribute__((ext_vector_type(4))) float;   // MFMA C/D

#define NPTS    1000000
#define NUMEMB  6572
#define HID     128
#define M_IT    64          // points per block-iteration
#define A0S     72          // A0 row stride in bf16 (144B, 16B-aligned rows)
#define H0S     136         // H0 row stride in bf16 (272B, 16B-aligned rows)
#define TILES   (NPTS / M_IT)   // 15625 exactly
#define NBLOCKS 768         // 3 blocks/CU on 256 CUs (proven non-spill rung)

__device__ __forceinline__ unsigned short bf16r(float f) {
    unsigned u;
    __builtin_memcpy(&u, &f, 4);
    u = (u + 0x7fffu + ((u >> 16) & 1u)) >> 16;
    return (unsigned short)u;
}
__device__ __forceinline__ unsigned pk2(float a, float b) {
    // packed RNE f32x2 -> bf16x2 (v_cvt_pk_bf16_f32 on gfx950)
    float2 f2; f2.x = a; f2.y = b;
    __hip_bfloat162 h = __float22bfloat162_rn(f2);
    unsigned u;
    __builtin_memcpy(&u, &h, 4);
    return u;
}
__device__ __forceinline__ unsigned pk2c(float a, float b) {
    // packed cvt with VOP3 clamp: result clamped to [0,1] — fuses clamp01
    unsigned r;
    asm("v_cvt_pk_bf16_f32 %0, %1, %2 clamp" : "=v"(r) : "v"(a), "v"(b));
    return r;
}
// LDS-only barrier: waits DS/SMEM queue, NOT vmem. Single asm block =>
// nothing schedules between the wait and the barrier; "memory" clobber
// pins all LDS accesses to their side of it.
__device__ __forceinline__ void bar_lds() {
    asm volatile("s_waitcnt lgkmcnt(0)\n\ts_barrier" ::: "memory");
}

__global__ __launch_bounds__(256, 3)
void mlp_fused(const float* __restrict__ x,
               const float* __restrict__ emb,
               const float* __restrict__ em_table,
               const float* __restrict__ W0, const float* __restrict__ b0,
               const float* __restrict__ W1, const float* __restrict__ b1,
               const float* __restrict__ W2, const float* __restrict__ b2,
               float* __restrict__ out)
{
    __shared__ __align__(16) unsigned short A0[M_IT * A0S];  // bf16 [pt][in]
    __shared__ __align__(16) unsigned short H0[M_IT * H0S];  // bf16 [pt][hperm]
    // PART[p][w] aliased into A0 bytes p*144 + 128 + w*4 (cols 64..71,
    // never accessed as A0: reads span cols <=63, writes cols <=33).

    const int tid  = threadIdx.x;
    const int lane = tid & 63;
    const int nq   = tid >> 6;   // wave's physical hidden block [nq*32,+32)
    const int q    = lane >> 4;  // quad within wave
    const int cl   = lane & 15;
    const int p    = tid >> 2;   // staging: point within tile
    const int s    = tid & 3;    // staging: 8-dim segment of embedding

    // zero A0 once (cols 34..63 stay zero forever; build overwrites 0..33)
    for (int i = tid; i < M_IT * A0S; i += 256) A0[i] = 0;

    // ---- one-time: weight A-fragments (permuted cols) into registers ----
    // A-frag lane (q,cl) holds A[m=cl][k=q*8+e]. Permuted physical hidden
    // for column m within block (nq,hb): h = nq*32 + (m>>2)*8 + hb*4 + (m&3).
    const int hcol = nq * 32 + (cl >> 2) * 8 + (cl & 3);  // + hb*4
    // W0 logical row k: k<32 -> em row 2+k ; k==32 -> x row 0 ; k==33 -> 1.
    bf16x8 w0t[2][2];   // [hb][kt]
    for (int hb = 0; hb < 2; ++hb)
        for (int kt = 0; kt < 2; ++kt) {
            const int col = hcol + hb * 4;
            bf16x8 v;
            #pragma unroll
            for (int e = 0; e < 8; ++e) {
                const int k = kt * 32 + q * 8 + e;
                float val = 0.f;
                if (k < 32)       val = W0[(2 + k) * HID + col];
                else if (k == 32) val = W0[0 * HID + col];
                else if (k == 33) val = W0[1 * HID + col];
                v[e] = (short)bf16r(val);
            }
            w0t[hb][kt] = v;
        }

    // W1 ROTATED: w1r[hb][kk] holds rows kphys = ((nq+kk)&3)*32 + q*8 + e
    bf16x8 w1r[2][4];   // [hb][kk]
    for (int hb = 0; hb < 2; ++hb)
        for (int kk = 0; kk < 4; ++kk) {
            const int kt  = (nq + kk) & 3;
            const int col = hcol + hb * 4;
            bf16x8 v;
            #pragma unroll
            for (int e = 0; e < 8; ++e) {
                const int k = kt * 32 + q * 8 + e;
                v[e] = (short)bf16r(W1[k * HID + col]);
            }
            w1r[hb][kk] = v;
        }

    // biases indexed by this lane's physical h = nq*32 + q*8 + hb*4 + r
    f32x4 b0q[2], b1q[2];
    for (int hb = 0; hb < 2; ++hb)
        for (int r = 0; r < 4; ++r) {
            const int h = nq * 32 + q * 8 + hb * 4 + r;
            b0q[hb][r] = b0[h];
            b1q[hb][r] = b1[h];
        }
    // L2 A-frag: A[m][k] = (m==0) ? W2[nq*32 + q*8 + k_e] : 0.
    // e enumerates hb*4+r in physical order 0..7, so W2 index is linear.
    bf16x8 w2f;
    #pragma unroll
    for (int e = 0; e < 8; ++e)
        w2f[e] = (cl == 0) ? (short)bf16r(W2[nq * 32 + q * 8 + e]) : (short)0;
    const float bias2 = b2[0];

    // ---- shallow prefetch: fe/x for the first tile (3 regs) ----
    int t = blockIdx.x;
    float  feA;
    float2 xvA = {0.f, 0.f};
    {
        const int gp = t * M_IT + p;
        feA = emb[gp];
        if (s == 0) xvA = *(const float2*)(x + 2 * gp);
    }

    __syncthreads();   // A0 zeroing visible before first build (cold path)

    for (; t < TILES; t += gridDim.x) {
        const int base = t * M_IT;

        // ---- stage inputs into A0 (gathers start immediately: feA ready) --
        {
            const int e1 = (int)feA;
            const int e2 = (e1 + 1 < NUMEMB) ? e1 + 1 : NUMEMB - 1;
            const float r = feA - (float)e1;
            const float4* p1 = (const float4*)(em_table + e1 * 32 + s * 8);
            const float4* p2 = (const float4*)(em_table + e2 * 32 + s * 8);
            const float4 a0v = p1[0], a1v = p1[1];
            const float4 c0v = p2[0], c1v = p2[1];
            uint4 d;
            d.x = pk2(a0v.x + (c0v.x - a0v.x) * r, a0v.y + (c0v.y - a0v.y) * r);
            d.y = pk2(a0v.z + (c0v.z - a0v.z) * r, a0v.w + (c0v.w - a0v.w) * r);
            d.z = pk2(a1v.x + (c1v.x - a1v.x) * r, a1v.y + (c1v.y - a1v.y) * r);
            d.w = pk2(a1v.z + (c1v.z - a1v.z) * r, a1v.w + (c1v.w - a1v.w) * r);
            *(uint4*)&A0[p * A0S + s * 8] = d;
            if (s == 0) *(unsigned*)&A0[p * A0S + 32] = pk2(xvA.x, xvA.y);
        }
        bar_lds();   // bar1: A0 visible (LDS-only; no vmcnt drain)

        // ---- layer 0 (transposed, permuted cols): bias rides C operand ----
        f32x4 acc[4][2];   // [pb][hb]
        #pragma unroll
        for (int pb = 0; pb < 4; ++pb) {
            const bf16x8 bf0 = *(const bf16x8*)&A0[(pb * 16 + cl) * A0S + q * 8];
            const bf16x8 bf1 = *(const bf16x8*)&A0[(pb * 16 + cl) * A0S + 32 + q * 8];
            #pragma unroll
            for (int hb = 0; hb < 2; ++hb) {
                f32x4 a = __builtin_amdgcn_mfma_f32_16x16x32_bf16(
                    w0t[hb][0], bf0, b0q[hb], 0, 0, 0);
                acc[pb][hb] = __builtin_amdgcn_mfma_f32_16x16x32_bf16(
                    w0t[hb][1], bf1, a, 0, 0, 0);
            }
        }

        // prefetch fe/x for next tile — NOT drained at barriers anymore;
        // latency covered until use at next tile's stage (~full tile away)
        {
            int t1 = t + gridDim.x; if (t1 >= TILES) t1 = t;
            const int gp = t1 * M_IT + p;
            feA = emb[gp];
            if (s == 0) xvA = *(const float2*)(x + 2 * gp);
        }

        // epi0: clamp fused into cvt (pk2c); straight to H0 (no own[]).
        #pragma unroll
        for (int pb = 0; pb < 4; ++pb) {
            const f32x4 v0 = acc[pb][0], v1 = acc[pb][1];
            uint4 w;
            w.x = pk2c(v0[0], v0[1]);
            w.y = pk2c(v0[2], v0[3]);
            w.z = pk2c(v1[0], v1[1]);
            w.w = pk2c(v1[2], v1[3]);
            *(uint4*)&H0[(pb * 16 + cl) * H0S + nq * 32 + q * 8] = w;
        }
        bar_lds();   // bar2: H0 visible (LDS-only; prefetch stays in flight)

        // ---- layer 1: all kt from LDS; bias rides C at kk==0 (literal) ----
        #pragma unroll
        for (int kk = 0; kk < 4; ++kk) {
            const int kcol = (((nq + kk) & 3) << 5) + q * 8;  // runtime addr
            #pragma unroll
            for (int pb = 0; pb < 4; ++pb) {
                bf16x8 bfrag = *(const bf16x8*)
                    &H0[(pb * 16 + cl) * H0S + kcol];
                #pragma unroll
                for (int hb = 0; hb < 2; ++hb)
                    acc[pb][hb] = __builtin_amdgcn_mfma_f32_16x16x32_bf16(
                        w1r[hb][kk], bfrag,
                        kk == 0 ? b1q[hb] : acc[pb][hb], 0, 0, 0);
            }
        }

        // ---- layer 2 via MFMA: clamped-h1 frag is the B operand; ----------
        // D[0][cl] (lanes q==0, reg 0) = dot over this wave's 32 hiddens.
        const f32x4 zero = {0.f, 0.f, 0.f, 0.f};
        #pragma unroll
        for (int pb = 0; pb < 4; ++pb) {
            const f32x4 v0 = acc[pb][0], v1 = acc[pb][1];
            uint4 w;
            w.x = pk2c(v0[0], v0[1]);
            w.y = pk2c(v0[2], v0[3]);
            w.z = pk2c(v1[0], v1[1]);
            w.w = pk2c(v1[2], v1[3]);
            bf16x8 hf;
            __builtin_memcpy(&hf, &w, 16);
            const f32x4 z4 = __builtin_amdgcn_mfma_f32_16x16x32_bf16(
                w2f, hf, zero, 0, 0, 0);
            if (q == 0)
                *(float*)((char*)A0 + (pb * 16 + cl) * 144 + 128 + nq * 4) = z4[0];
        }
        bar_lds();   // bar3: PART visible (LDS-only)

        if (tid < 64) {
            const float4 pv = *(const float4*)((const char*)A0 + tid * 144 + 128);
            const float zz = bias2 + pv.x + pv.y + pv.z + pv.w;
            out[base + tid] = __builtin_amdgcn_rcpf(1.f + __expf(-zz));
        }
        // hazards: A0[cols 0..33] rewrite (next stage) is 2 barriers after
        // L0 reads; H0 rewrite 2 barriers after L1 reads; PART (A0 cols
        // 64..71) write->read has bar3, read->next-write has bar1+bar2;
        // stage(t+1) writes cols 0..33 only, disjoint from out-read bytes.
        // All barrier-protected deps are LDS => lgkmcnt(0) suffices; every
        // global load is consumed by its issuing wave (per-use vmcnt).
    }
}

extern "C" void kernel_launch(void* const* d_in, const int* in_sizes, int n_in,
                              void* d_out, int out_size, void* d_ws, size_t ws_size,
                              hipStream_t stream) {
    const float* x   = (const float*)d_in[0];
    const float* emb = (const float*)d_in[1];
    const float* emt = (const float*)d_in[2];
    const float* W0  = (const float*)d_in[3];
    const float* b0  = (const float*)d_in[4];
    const float* W1  = (const float*)d_in[5];
    const float* b1  = (const float*)d_in[6];
    const float* W2  = (const float*)d_in[7];
    const float* b2  = (const float*)d_in[8];
    mlp_fused<<<NBLOCKS, 256, 0, stream>>>(x, emb, emt, W0, b0, W1, b1, W2, b2,
                                           (float*)d_out);
}

// Round 11
// 120.631 us; speedup vs baseline: 1.2828x; 1.0222x over previous
//
#include <hip/hip_runtime.h>
#include <hip/hip_bf16.h>

// Fused 34->128->128->1 MLP, bf16 MFMA, transposed GEMMs.
// R21 = R18 (proven best, 60.3us) with bar3 DELETED via out-phase deferral.
// R19/R20 post-mortem: half-split 2-wave family NaN'd twice with no
// source-visible cause (all math re-audited correct; all values provably
// finite via pk2c clamp) => codegen-level gremlin; branch abandoned per
// anti-gambling rule. Optimize inside the proven 4-wave structure instead.
// R21 change: PART(t) is written in [bar2(t), bar1(t+1)); the out-read of
// tile t moves to just after bar1(t+1) (overlapping L0(t+1) MFMAs of the
// other waves) instead of a dedicated bar3. 3 -> 2 barriers/tile.
// Hazard audit (bar_lds = per-wave s_waitcnt lgkmcnt(0) + s_barrier):
//  - PART-writes(t) drained before each wave enters bar1(t+1)  -> visible.
//  - out-reads(t) drained before wave0 enters bar2(t+1); PART-writes(t+1)
//    happen after bar2(t+1)  -> no WAR clash.
//  - stage(t+1) writes A0 cols 0..33; out reads cols 64..71: disjoint.
//  - stage(t+1) vs L0(t) reads: separated by bar2(t).
//  - epi0(t+1) H0-writes vs L1(t) reads: separated by bar1(t+1).
// Epilogue: trailing bar_lds + out flush for the last tile.
// Kept verbatim from R18 (all verified): lgkm-only barriers (vmcnt stays
// in flight across barriers), pk2c clamp-fused cvt, L2-as-MFMA (W2 in A
// row 0), biases ride first MFMA C, PART aliased in A0 cols 64..71
// (LDS 26624B), no own[] (NaN cell R14), w1r rotation (literal indices).
// R8a: phys h = nq*32 + q*8 + hb*4 + r; L0 C/D frag == L1 B frag layout.
// Spill tell: WRITE_SIZE == 3906.25KB <=> clean alloc at (256,3).

using bf16x8 = __attribute__((ext_vector_type(8))) short;   // 8 bf16 = 4 VGPRs
using f32x4  = __attribute__((ext_vector_type(4))) float;   // MFMA C/D

#define NPTS    1000000
#define NUMEMB  6572
#define HID     128
#define M_IT    64          // points per block-iteration
#define A0S     72          // A0 row stride in bf16 (144B, 16B-aligned rows)
#define H0S     136         // H0 row stride in bf16 (272B, 16B-aligned rows)
#define TILES   (NPTS / M_IT)   // 15625 exactly
#define NBLOCKS 768         // 3 blocks/CU on 256 CUs (proven non-spill rung)

__device__ __forceinline__ unsigned short bf16r(float f) {
    unsigned u;
    __builtin_memcpy(&u, &f, 4);
    u = (u + 0x7fffu + ((u >> 16) & 1u)) >> 16;
    return (unsigned short)u;
}
__device__ __forceinline__ unsigned pk2(float a, float b) {
    // packed RNE f32x2 -> bf16x2 (v_cvt_pk_bf16_f32 on gfx950)
    float2 f2; f2.x = a; f2.y = b;
    __hip_bfloat162 h = __float22bfloat162_rn(f2);
    unsigned u;
    __builtin_memcpy(&u, &h, 4);
    return u;
}
__device__ __forceinline__ unsigned pk2c(float a, float b) {
    // packed cvt with VOP3 clamp: result clamped to [0,1] — fuses clamp01
    unsigned r;
    asm("v_cvt_pk_bf16_f32 %0, %1, %2 clamp" : "=v"(r) : "v"(a), "v"(b));
    return r;
}
// LDS-only barrier: waits DS/SMEM queue, NOT vmem. Single asm block =>
// nothing schedules between the wait and the barrier; "memory" clobber
// pins all LDS accesses to their side of it. (R18-verified.)
__device__ __forceinline__ void bar_lds() {
    asm volatile("s_waitcnt lgkmcnt(0)\n\ts_barrier" ::: "memory");
}

__global__ __launch_bounds__(256, 3)
void mlp_fused(const float* __restrict__ x,
               const float* __restrict__ emb,
               const float* __restrict__ em_table,
               const float* __restrict__ W0, const float* __restrict__ b0,
               const float* __restrict__ W1, const float* __restrict__ b1,
               const float* __restrict__ W2, const float* __restrict__ b2,
               float* __restrict__ out)
{
    __shared__ __align__(16) unsigned short A0[M_IT * A0S];  // bf16 [pt][in]
    __shared__ __align__(16) unsigned short H0[M_IT * H0S];  // bf16 [pt][hperm]
    // PART[p][w] aliased into A0 bytes p*144 + 128 + w*4 (cols 64..71,
    // never accessed as A0: reads span cols <=63, writes cols <=33).

    const int tid  = threadIdx.x;
    const int lane = tid & 63;
    const int nq   = tid >> 6;   // wave's physical hidden block [nq*32,+32)
    const int q    = lane >> 4;  // quad within wave
    const int cl   = lane & 15;
    const int p    = tid >> 2;   // staging: point within tile
    const int s    = tid & 3;    // staging: 8-dim segment of embedding

    // zero A0 once (cols 34..63 stay zero forever; build overwrites 0..33)
    for (int i = tid; i < M_IT * A0S; i += 256) A0[i] = 0;

    // ---- one-time: weight A-fragments (permuted cols) into registers ----
    // A-frag lane (q,cl) holds A[m=cl][k=q*8+e]. Permuted physical hidden
    // for column m within block (nq,hb): h = nq*32 + (m>>2)*8 + hb*4 + (m&3).
    const int hcol = nq * 32 + (cl >> 2) * 8 + (cl & 3);  // + hb*4
    // W0 logical row k: k<32 -> em row 2+k ; k==32 -> x row 0 ; k==33 -> 1.
    bf16x8 w0t[2][2];   // [hb][kt]
    for (int hb = 0; hb < 2; ++hb)
        for (int kt = 0; kt < 2; ++kt) {
            const int col = hcol + hb * 4;
            bf16x8 v;
            #pragma unroll
            for (int e = 0; e < 8; ++e) {
                const int k = kt * 32 + q * 8 + e;
                float val = 0.f;
                if (k < 32)       val = W0[(2 + k) * HID + col];
                else if (k == 32) val = W0[0 * HID + col];
                else if (k == 33) val = W0[1 * HID + col];
                v[e] = (short)bf16r(val);
            }
            w0t[hb][kt] = v;
        }

    // W1 ROTATED: w1r[hb][kk] holds rows kphys = ((nq+kk)&3)*32 + q*8 + e
    bf16x8 w1r[2][4];   // [hb][kk]
    for (int hb = 0; hb < 2; ++hb)
        for (int kk = 0; kk < 4; ++kk) {
            const int kt  = (nq + kk) & 3;
            const int col = hcol + hb * 4;
            bf16x8 v;
            #pragma unroll
            for (int e = 0; e < 8; ++e) {
                const int k = kt * 32 + q * 8 + e;
                v[e] = (short)bf16r(W1[k * HID + col]);
            }
            w1r[hb][kk] = v;
        }

    // biases indexed by this lane's physical h = nq*32 + q*8 + hb*4 + r
    f32x4 b0q[2], b1q[2];
    for (int hb = 0; hb < 2; ++hb)
        for (int r = 0; r < 4; ++r) {
            const int h = nq * 32 + q * 8 + hb * 4 + r;
            b0q[hb][r] = b0[h];
            b1q[hb][r] = b1[h];
        }
    // L2 A-frag: A[m][k] = (m==0) ? W2[nq*32 + q*8 + k_e] : 0.
    // e enumerates hb*4+r in physical order 0..7, so W2 index is linear.
    bf16x8 w2f;
    #pragma unroll
    for (int e = 0; e < 8; ++e)
        w2f[e] = (cl == 0) ? (short)bf16r(W2[nq * 32 + q * 8 + e]) : (short)0;
    const float bias2 = b2[0];

    // ---- shallow prefetch: fe/x for the first tile (3 regs) ----
    int t = blockIdx.x;
    float  feA;
    float2 xvA = {0.f, 0.f};
    {
        const int gp = t * M_IT + p;
        feA = emb[gp];
        if (s == 0) xvA = *(const float2*)(x + 2 * gp);
    }

    __syncthreads();   // A0 zeroing visible before first build (cold path)

    int prev_base = -1;   // out-phase is deferred one tile (bar3 deleted)

    for (; t < TILES; t += gridDim.x) {
        const int base = t * M_IT;

        // ---- stage inputs into A0 (gathers start immediately: feA ready) --
        {
            const int e1 = (int)feA;
            const int e2 = (e1 + 1 < NUMEMB) ? e1 + 1 : NUMEMB - 1;
            const float r = feA - (float)e1;
            const float4* p1 = (const float4*)(em_table + e1 * 32 + s * 8);
            const float4* p2 = (const float4*)(em_table + e2 * 32 + s * 8);
            const float4 a0v = p1[0], a1v = p1[1];
            const float4 c0v = p2[0], c1v = p2[1];
            uint4 d;
            d.x = pk2(a0v.x + (c0v.x - a0v.x) * r, a0v.y + (c0v.y - a0v.y) * r);
            d.y = pk2(a0v.z + (c0v.z - a0v.z) * r, a0v.w + (c0v.w - a0v.w) * r);
            d.z = pk2(a1v.x + (c1v.x - a1v.x) * r, a1v.y + (c1v.y - a1v.y) * r);
            d.w = pk2(a1v.z + (c1v.z - a1v.z) * r, a1v.w + (c1v.w - a1v.w) * r);
            *(uint4*)&A0[p * A0S + s * 8] = d;
            if (s == 0) *(unsigned*)&A0[p * A0S + 32] = pk2(xvA.x, xvA.y);
        }
        bar_lds();   // bar1: A0(t) + PART(t-1) visible (LDS-only)

        // ---- deferred out-phase for tile t-1 (overlaps L0 below) ----
        if (prev_base >= 0 && tid < 64) {
            const float4 pv = *(const float4*)((const char*)A0 + tid * 144 + 128);
            const float zz = bias2 + pv.x + pv.y + pv.z + pv.w;
            out[prev_base + tid] = __builtin_amdgcn_rcpf(1.f + __expf(-zz));
        }

        // ---- layer 0 (transposed, permuted cols): bias rides C operand ----
        f32x4 acc[4][2];   // [pb][hb]
        #pragma unroll
        for (int pb = 0; pb < 4; ++pb) {
            const bf16x8 bf0 = *(const bf16x8*)&A0[(pb * 16 + cl) * A0S + q * 8];
            const bf16x8 bf1 = *(const bf16x8*)&A0[(pb * 16 + cl) * A0S + 32 + q * 8];
            #pragma unroll
            for (int hb = 0; hb < 2; ++hb) {
                f32x4 a = __builtin_amdgcn_mfma_f32_16x16x32_bf16(
                    w0t[hb][0], bf0, b0q[hb], 0, 0, 0);
                acc[pb][hb] = __builtin_amdgcn_mfma_f32_16x16x32_bf16(
                    w0t[hb][1], bf1, a, 0, 0, 0);
            }
        }

        // prefetch fe/x for next tile — never drained at barriers (lgkm-only)
        {
            int t1 = t + gridDim.x; if (t1 >= TILES) t1 = t;
            const int gp = t1 * M_IT + p;
            feA = emb[gp];
            if (s == 0) xvA = *(const float2*)(x + 2 * gp);
        }

        // epi0: clamp fused into cvt (pk2c); straight to H0 (no own[]).
        #pragma unroll
        for (int pb = 0; pb < 4; ++pb) {
            const f32x4 v0 = acc[pb][0], v1 = acc[pb][1];
            uint4 w;
            w.x = pk2c(v0[0], v0[1]);
            w.y = pk2c(v0[2], v0[3]);
            w.z = pk2c(v1[0], v1[1]);
            w.w = pk2c(v1[2], v1[3]);
            *(uint4*)&H0[(pb * 16 + cl) * H0S + nq * 32 + q * 8] = w;
        }
        bar_lds();   // bar2: H0 visible; wave0's out-reads drained by its own
                     // lgkmcnt before entering (PART(t) writes come after)

        // ---- layer 1: all kt from LDS; bias rides C at kk==0 (literal) ----
        #pragma unroll
        for (int kk = 0; kk < 4; ++kk) {
            const int kcol = (((nq + kk) & 3) << 5) + q * 8;  // runtime addr
            #pragma unroll
            for (int pb = 0; pb < 4; ++pb) {
                bf16x8 bfrag = *(const bf16x8*)
                    &H0[(pb * 16 + cl) * H0S + kcol];
                #pragma unroll
                for (int hb = 0; hb < 2; ++hb)
                    acc[pb][hb] = __builtin_amdgcn_mfma_f32_16x16x32_bf16(
                        w1r[hb][kk], bfrag,
                        kk == 0 ? b1q[hb] : acc[pb][hb], 0, 0, 0);
            }
        }

        // ---- layer 2 via MFMA: clamped-h1 frag is the B operand; ----------
        // D[0][cl] (lanes q==0, reg 0) = dot over this wave's 32 hiddens.
        const f32x4 zero = {0.f, 0.f, 0.f, 0.f};
        #pragma unroll
        for (int pb = 0; pb < 4; ++pb) {
            const f32x4 v0 = acc[pb][0], v1 = acc[pb][1];
            uint4 w;
            w.x = pk2c(v0[0], v0[1]);
            w.y = pk2c(v0[2], v0[3]);
            w.z = pk2c(v1[0], v1[1]);
            w.w = pk2c(v1[2], v1[3]);
            bf16x8 hf;
            __builtin_memcpy(&hf, &w, 16);
            const f32x4 z4 = __builtin_amdgcn_mfma_f32_16x16x32_bf16(
                w2f, hf, zero, 0, 0, 0);
            if (q == 0)
                *(float*)((char*)A0 + (pb * 16 + cl) * 144 + 128 + nq * 4) = z4[0];
        }
        prev_base = base;   // out for this tile happens after next bar1
        // (no bar3 — next loop top: stage(t+1) [cols 0..33, disjoint from
        //  PART] then bar1(t+1) orders PART(t) writes before the out-read)

        // hazards: A0 cols0..33 rewrite (next stage) vs L0(t) reads -> bar2;
        // H0 rewrite (epi0 t+1) vs L1(t) reads -> bar1(t+1); PART(t) write
        // -> out-read(t) -> PART(t+1) write ordered by bar1(t+1)/bar2(t+1).
    }

    // epilogue: flush the last tile's deferred out-phase
    bar_lds();
    if (prev_base >= 0 && tid < 64) {
        const float4 pv = *(const float4*)((const char*)A0 + tid * 144 + 128);
        const float zz = bias2 + pv.x + pv.y + pv.z + pv.w;
        out[prev_base + tid] = __builtin_amdgcn_rcpf(1.f + __expf(-zz));
    }
}

extern "C" void kernel_launch(void* const* d_in, const int* in_sizes, int n_in,
                              void* d_out, int out_size, void* d_ws, size_t ws_size,
                              hipStream_t stream) {
    const float* x   = (const float*)d_in[0];
    const float* emb = (const float*)d_in[1];
    const float* emt = (const float*)d_in[2];
    const float* W0  = (const float*)d_in[3];
    const float* b0  = (const float*)d_in[4];
    const float* W1  = (const float*)d_in[5];
    const float* b1  = (const float*)d_in[6];
    const float* W2  = (const float*)d_in[7];
    const float* b2  = (const float*)d_in[8];
    mlp_fused<<<NBLOCKS, 256, 0, stream>>>(x, emb, emt, W0, b0, W1, b1, W2, b2,
                                           (float*)d_out);
}